// Round 1
// 790.271 us; speedup vs baseline: 3.6355x; 3.6355x over previous
//
#include <hip/hip_runtime.h>

#define TPB 256

// ---- LDS-binned scatter parameters ----
#define SCAT_TPB 1024       // 16 waves/block, 2 blocks/CU (LDS-limited) = 32 waves/CU
#define S_RANGE  8064       // nodes per LDS slab; 2*8064*4 = 64512 B < 64 KiB static LDS
#define SCAT_GRID 512       // 2 blocks/CU * 256 CU -> all blocks co-resident

__device__ __forceinline__ unsigned xcc_id() {
    unsigned v;
    asm volatile("s_getreg_b32 %0, hwreg(HW_REG_XCC_ID)" : "=s"(v));
    return v & 7u;
}

// replicas: R copies of [out_deg (N) | in_deg (N)] back to back in ws.
// R computed identically on device in every kernel: min(8, ws_floats/(2N)).
__device__ __forceinline__ int calc_R(unsigned long long ws_bytes, int N) {
    unsigned long long ws_floats = ws_bytes / 4ull;
    unsigned long long r = ws_floats / (unsigned long long)(2 * N);
    if (r > 8ull) r = 8ull;
    if (r < 1ull) r = 1ull;
    return (int)r;
}

// ---- kernel 1: zero R*2N floats of replica space ----
__global__ void ewn_zero_kernel(float* __restrict__ ws,
                                const int* __restrict__ pN,
                                unsigned long long ws_bytes) {
    int N = *pN;
    int R = calc_R(ws_bytes, N);
    long long total = (long long)R * 2 * N;
    for (long long i = blockIdx.x * (long long)blockDim.x + threadIdx.x; i < total;
         i += (long long)gridDim.x * blockDim.x) {
        ws[i] = 0.0f;
    }
}

// ---- kernel 2: node-range-partitioned LDS histogram scatter ----
// Grid decomposes into NR node-ranges x M edge-stripes. Block (r,m) scans
// stripe m of the edge list and accumulates, in LDS, contributions to nodes
// in [r*S_RANGE, (r+1)*S_RANGE) for BOTH the src (out-deg) and dst (in-deg)
// histograms. Flush: S_RANGE coalesced workgroup-scope atomics into the
// per-XCD replica (same replica layout as before).
// Global atomics: 51.2M random -> ~8.2M coalesced. RMW moves to ds_add_f32.
// Block ids are m*NR + r, so the NR blocks sharing stripe m are consecutive:
// dispatched together -> they read the same edge chunk concurrently and the
// 13x scan is served by L3 multicast (input ~300 MB vs 256 MB L3).
__global__ __launch_bounds__(SCAT_TPB, 8) void ewn_scatter_kernel(
        const float* __restrict__ w,
        const int* __restrict__ src,
        const int* __restrict__ dst,
        float* __restrict__ ws,
        const int* __restrict__ pN,
        unsigned long long ws_bytes,
        int E) {
    __shared__ float h_out[S_RANGE];
    __shared__ float h_in[S_RANGE];

    const int N = *pN;
    const int R = calc_R(ws_bytes, N);

    int NR = (N + S_RANGE - 1) / S_RANGE;   // 13 for N=100K
    if (NR < 1) NR = 1;
    int M = (int)gridDim.x / NR;            // 39 stripes
    if (M < 1) M = 1;

    const int bid = blockIdx.x;
    if (bid >= NR * M) return;              // 5 idle blocks at 512-grid
    const int m = bid / NR;                 // stripe index
    const int r = bid % NR;                 // node-range index
    const int lo = r * S_RANGE;

    // zero LDS histograms
    for (int i = threadIdx.x; i < S_RANGE; i += SCAT_TPB) {
        h_out[i] = 0.0f;
        h_in[i]  = 0.0f;
    }
    __syncthreads();

    // stripe bounds, 4-element aligned so float4/int4 loads stay 16B-aligned
    long long stripe = (((long long)E + M - 1) / M + 3ll) & ~3ll;
    long long jstart = (long long)m * stripe;
    long long jend   = jstart + stripe;
    if (jend > E) jend = E;

    for (long long j0 = jstart + (long long)threadIdx.x * 4; j0 < jend;
         j0 += (long long)SCAT_TPB * 4) {
        if (j0 + 3 < jend) {
            float4 wv = *(const float4*)(w + j0);
            int4   sv = *(const int4*)(src + j0);
            int4   dv = *(const int4*)(dst + j0);
            int t;
            t = sv.x - lo; if ((unsigned)t < (unsigned)S_RANGE) unsafeAtomicAdd(&h_out[t], wv.x);
            t = sv.y - lo; if ((unsigned)t < (unsigned)S_RANGE) unsafeAtomicAdd(&h_out[t], wv.y);
            t = sv.z - lo; if ((unsigned)t < (unsigned)S_RANGE) unsafeAtomicAdd(&h_out[t], wv.z);
            t = sv.w - lo; if ((unsigned)t < (unsigned)S_RANGE) unsafeAtomicAdd(&h_out[t], wv.w);
            t = dv.x - lo; if ((unsigned)t < (unsigned)S_RANGE) unsafeAtomicAdd(&h_in[t],  wv.x);
            t = dv.y - lo; if ((unsigned)t < (unsigned)S_RANGE) unsafeAtomicAdd(&h_in[t],  wv.y);
            t = dv.z - lo; if ((unsigned)t < (unsigned)S_RANGE) unsafeAtomicAdd(&h_in[t],  wv.z);
            t = dv.w - lo; if ((unsigned)t < (unsigned)S_RANGE) unsafeAtomicAdd(&h_in[t],  wv.w);
        } else {
            long long jhi = j0 + 4 < jend ? j0 + 4 : jend;
            for (long long j = j0; j < jhi; ++j) {
                float wj = w[j];
                int t;
                t = src[j] - lo; if ((unsigned)t < (unsigned)S_RANGE) unsafeAtomicAdd(&h_out[t], wj);
                t = dst[j] - lo; if ((unsigned)t < (unsigned)S_RANGE) unsafeAtomicAdd(&h_in[t],  wj);
            }
        }
    }
    __syncthreads();

    // flush LDS histograms with coalesced atomics into per-XCD replica
    const unsigned xcc = xcc_id();
    int hi = N - lo;
    if (hi > S_RANGE) hi = S_RANGE;

    if (R == 8) {
        float* deg_out = ws + (unsigned long long)xcc * 2ull * N;
        float* deg_in  = deg_out + N;
        for (int i = threadIdx.x; i < hi; i += SCAT_TPB) {
            __hip_atomic_fetch_add(&deg_out[lo + i], h_out[i], __ATOMIC_RELAXED, __HIP_MEMORY_SCOPE_WORKGROUP);
            __hip_atomic_fetch_add(&deg_in[lo + i],  h_in[i],  __ATOMIC_RELAXED, __HIP_MEMORY_SCOPE_WORKGROUP);
        }
    } else {
        // fallback (ws too small for 8 replicas): device-scope atomics, always correct
        float* deg_out = ws + (unsigned long long)(xcc % (unsigned)R) * 2ull * N;
        float* deg_in  = deg_out + N;
        for (int i = threadIdx.x; i < hi; i += SCAT_TPB) {
            atomicAdd(&deg_out[lo + i], h_out[i]);
            atomicAdd(&deg_in[lo + i],  h_in[i]);
        }
    }
}

// ---- kernel 3: reduce R replicas + rsqrt, result into replica 0 ----
__global__ void ewn_reduce_norm_kernel(float* __restrict__ ws,
                                       const int* __restrict__ pN,
                                       unsigned long long ws_bytes) {
    int N = *pN;
    int R = calc_R(ws_bytes, N);
    long long n2 = 2ll * N;
    for (long long i = blockIdx.x * (long long)blockDim.x + threadIdx.x; i < n2;
         i += (long long)gridDim.x * blockDim.x) {
        float s = 0.0f;
        for (int r = 0; r < R; ++r) s += ws[(long long)r * n2 + i];
        ws[i] = 1.0f / sqrtf(s);   // precise rsqrt to stay under absmax threshold
    }
}

// ---- kernel 4: out[e] = norm_out[src[e]] * norm_in[dst[e]] * w[e] ----
__global__ void ewn_gather_kernel(const float* __restrict__ w,
                                  const int* __restrict__ src,
                                  const int* __restrict__ dst,
                                  const float* __restrict__ ws,
                                  const int* __restrict__ pN,
                                  float* __restrict__ out,
                                  int E) {
    const int N = *pN;
    const float* norm_out = ws;
    const float* norm_in  = ws + N;
    int i = blockIdx.x * blockDim.x + threadIdx.x;
    long long i4 = (long long)i * 4;
    if (i4 + 3 < E) {
        float4 wv = *(const float4*)(w + i4);
        int4  sv = *(const int4*)(src + i4);
        int4  dv = *(const int4*)(dst + i4);
        float4 ov;
        ov.x = norm_out[sv.x] * norm_in[dv.x] * wv.x;
        ov.y = norm_out[sv.y] * norm_in[dv.y] * wv.y;
        ov.z = norm_out[sv.z] * norm_in[dv.z] * wv.z;
        ov.w = norm_out[sv.w] * norm_in[dv.w] * wv.w;
        *(float4*)(out + i4) = ov;
    } else if (i4 < E) {
        for (long long j = i4; j < E; ++j) {
            out[j] = norm_out[src[j]] * norm_in[dst[j]] * w[j];
        }
    }
}

extern "C" void kernel_launch(void* const* d_in, const int* in_sizes, int n_in,
                              void* d_out, int out_size, void* d_ws, size_t ws_size,
                              hipStream_t stream) {
    const float* edge_weight = (const float*)d_in[0];
    const int*   src         = (const int*)d_in[1];
    const int*   dst         = (const int*)d_in[2];
    const int*   pN          = (const int*)d_in[3];  // 1-element device array
    float* out = (float*)d_out;
    const int E = in_sizes[0];
    float* ws = (float*)d_ws;
    unsigned long long wsb = (unsigned long long)ws_size;

    int nBlocksEdges = (E / 4 + TPB - 1) / TPB;

    ewn_zero_kernel<<<1024, TPB, 0, stream>>>(ws, pN, wsb);
    ewn_scatter_kernel<<<SCAT_GRID, SCAT_TPB, 0, stream>>>(edge_weight, src, dst, ws, pN, wsb, E);
    ewn_reduce_norm_kernel<<<1024, TPB, 0, stream>>>(ws, pN, wsb);
    ewn_gather_kernel<<<nBlocksEdges, TPB, 0, stream>>>(edge_weight, src, dst, ws, pN, out, E);
}

// Round 3
// 711.753 us; speedup vs baseline: 4.0366x; 1.1103x over previous
//
#include <hip/hip_runtime.h>

#define TPB 256

// clang ext_vector types for nontemporal builtins (HIP_vector_type is rejected)
typedef float ntf4 __attribute__((ext_vector_type(4)));
typedef int   nti4 __attribute__((ext_vector_type(4)));

// ---- LDS-binned scatter parameters ----
// One block per CU using (nearly) the full 160 KiB LDS:
// 2 slabs x 20352 x 4B = 162816 B <= 163840 B (gfx950 LDS/CU).
// NR = ceil(100000/20352) = 5 scans of the edge list (was 13 at 64.5 KiB).
#define SCAT_TPB 1024
#define S_RANGE  20352
#define SCAT_GRID 255       // NR(5) * M(51), all co-resident at 1 block/CU

__device__ __forceinline__ unsigned xcc_id() {
    unsigned v;
    asm volatile("s_getreg_b32 %0, hwreg(HW_REG_XCC_ID)" : "=s"(v));
    return v & 7u;
}

// replicas: R copies of [out_deg (N) | in_deg (N)] back to back in ws.
// R computed identically on device in every kernel: min(8, ws_floats/(2N)).
__device__ __forceinline__ int calc_R(unsigned long long ws_bytes, int N) {
    unsigned long long ws_floats = ws_bytes / 4ull;
    unsigned long long r = ws_floats / (unsigned long long)(2 * N);
    if (r > 8ull) r = 8ull;
    if (r < 1ull) r = 1ull;
    return (int)r;
}

// ---- kernel 1: zero R*2N floats of replica space ----
__global__ void ewn_zero_kernel(float* __restrict__ ws,
                                const int* __restrict__ pN,
                                unsigned long long ws_bytes) {
    int N = *pN;
    int R = calc_R(ws_bytes, N);
    long long total = (long long)R * 2 * N;
    for (long long i = blockIdx.x * (long long)blockDim.x + threadIdx.x; i < total;
         i += (long long)gridDim.x * blockDim.x) {
        ws[i] = 0.0f;
    }
}

// ---- kernel 2: node-range-partitioned LDS histogram scatter ----
// Grid decomposes into NR node-ranges x M edge-stripes. Block (r,m) scans
// stripe m of the edge list and accumulates, in LDS, contributions to nodes
// in [r*S_RANGE, (r+1)*S_RANGE) for BOTH the src (out-deg) and dst (in-deg)
// histograms. Flush: coalesced workgroup-scope atomics into per-XCD replica.
// Block ids are m*NR + r, so the NR blocks sharing stripe m are consecutive:
// dispatched together -> concurrent reads of the same edge chunk -> L3
// multicast serves the NR-x scan (total request traffic NR x 300 MB).
__global__ __launch_bounds__(SCAT_TPB, 4) void ewn_scatter_kernel(
        const float* __restrict__ w,
        const int* __restrict__ src,
        const int* __restrict__ dst,
        float* __restrict__ ws,
        const int* __restrict__ pN,
        unsigned long long ws_bytes,
        int E) {
    __shared__ float h_out[S_RANGE];
    __shared__ float h_in[S_RANGE];

    const int N = *pN;
    const int R = calc_R(ws_bytes, N);

    int NR = (N + S_RANGE - 1) / S_RANGE;   // 5 for N=100K
    if (NR < 1) NR = 1;
    int M = (int)gridDim.x / NR;            // 51 stripes
    if (M < 1) M = 1;

    const int bid = blockIdx.x;
    if (bid >= NR * M) return;
    const int m = bid / NR;                 // stripe index
    const int r = bid % NR;                 // node-range index
    const int lo = r * S_RANGE;

    // zero LDS histograms
    for (int i = threadIdx.x; i < S_RANGE; i += SCAT_TPB) {
        h_out[i] = 0.0f;
        h_in[i]  = 0.0f;
    }
    __syncthreads();

    // stripe bounds, 4-element aligned so float4/int4 loads stay 16B-aligned
    long long stripe = (((long long)E + M - 1) / M + 3ll) & ~3ll;
    long long jstart = (long long)m * stripe;
    long long jend   = jstart + stripe;
    if (jend > E) jend = E;

    for (long long j0 = jstart + (long long)threadIdx.x * 4; j0 < jend;
         j0 += (long long)SCAT_TPB * 4) {
        if (j0 + 3 < jend) {
            float4 wv = *(const float4*)(w + j0);
            int4   sv = *(const int4*)(src + j0);
            int4   dv = *(const int4*)(dst + j0);
            int t;
            t = sv.x - lo; if ((unsigned)t < (unsigned)S_RANGE) unsafeAtomicAdd(&h_out[t], wv.x);
            t = sv.y - lo; if ((unsigned)t < (unsigned)S_RANGE) unsafeAtomicAdd(&h_out[t], wv.y);
            t = sv.z - lo; if ((unsigned)t < (unsigned)S_RANGE) unsafeAtomicAdd(&h_out[t], wv.z);
            t = sv.w - lo; if ((unsigned)t < (unsigned)S_RANGE) unsafeAtomicAdd(&h_out[t], wv.w);
            t = dv.x - lo; if ((unsigned)t < (unsigned)S_RANGE) unsafeAtomicAdd(&h_in[t],  wv.x);
            t = dv.y - lo; if ((unsigned)t < (unsigned)S_RANGE) unsafeAtomicAdd(&h_in[t],  wv.y);
            t = dv.z - lo; if ((unsigned)t < (unsigned)S_RANGE) unsafeAtomicAdd(&h_in[t],  wv.z);
            t = dv.w - lo; if ((unsigned)t < (unsigned)S_RANGE) unsafeAtomicAdd(&h_in[t],  wv.w);
        } else {
            long long jhi = j0 + 4 < jend ? j0 + 4 : jend;
            for (long long j = j0; j < jhi; ++j) {
                float wj = w[j];
                int t;
                t = src[j] - lo; if ((unsigned)t < (unsigned)S_RANGE) unsafeAtomicAdd(&h_out[t], wj);
                t = dst[j] - lo; if ((unsigned)t < (unsigned)S_RANGE) unsafeAtomicAdd(&h_in[t],  wj);
            }
        }
    }
    __syncthreads();

    // flush LDS histograms with coalesced atomics into per-XCD replica
    const unsigned xcc = xcc_id();
    int hi = N - lo;
    if (hi > S_RANGE) hi = S_RANGE;

    if (R == 8) {
        float* deg_out = ws + (unsigned long long)xcc * 2ull * N;
        float* deg_in  = deg_out + N;
        for (int i = threadIdx.x; i < hi; i += SCAT_TPB) {
            __hip_atomic_fetch_add(&deg_out[lo + i], h_out[i], __ATOMIC_RELAXED, __HIP_MEMORY_SCOPE_WORKGROUP);
            __hip_atomic_fetch_add(&deg_in[lo + i],  h_in[i],  __ATOMIC_RELAXED, __HIP_MEMORY_SCOPE_WORKGROUP);
        }
    } else {
        // fallback (ws too small for 8 replicas): device-scope atomics, always correct
        float* deg_out = ws + (unsigned long long)(xcc % (unsigned)R) * 2ull * N;
        float* deg_in  = deg_out + N;
        for (int i = threadIdx.x; i < hi; i += SCAT_TPB) {
            atomicAdd(&deg_out[lo + i], h_out[i]);
            atomicAdd(&deg_in[lo + i],  h_in[i]);
        }
    }
}

// ---- kernel 3: reduce R replicas + rsqrt, result into replica 0 ----
__global__ void ewn_reduce_norm_kernel(float* __restrict__ ws,
                                       const int* __restrict__ pN,
                                       unsigned long long ws_bytes) {
    int N = *pN;
    int R = calc_R(ws_bytes, N);
    long long n2 = 2ll * N;
    for (long long i = blockIdx.x * (long long)blockDim.x + threadIdx.x; i < n2;
         i += (long long)gridDim.x * blockDim.x) {
        float s = 0.0f;
        for (int r = 0; r < R; ++r) s += ws[(long long)r * n2 + i];
        ws[i] = 1.0f / sqrtf(s);   // precise rsqrt to stay under absmax threshold
    }
}

// ---- kernel 4: out[e] = norm_out[src[e]] * norm_in[dst[e]] * w[e] ----
// Edge streams (w/src/dst/out) are non-temporal so the 800 KB norm tables
// stay resident in each XCD's L2.
__global__ void ewn_gather_kernel(const float* __restrict__ w,
                                  const int* __restrict__ src,
                                  const int* __restrict__ dst,
                                  const float* __restrict__ ws,
                                  const int* __restrict__ pN,
                                  float* __restrict__ out,
                                  int E) {
    const int N = *pN;
    const float* norm_out = ws;
    const float* norm_in  = ws + N;
    int i = blockIdx.x * blockDim.x + threadIdx.x;
    long long i4 = (long long)i * 4;
    if (i4 + 3 < E) {
        ntf4 wv = __builtin_nontemporal_load((const ntf4*)(w + i4));
        nti4 sv = __builtin_nontemporal_load((const nti4*)(src + i4));
        nti4 dv = __builtin_nontemporal_load((const nti4*)(dst + i4));
        ntf4 ov;
        ov.x = norm_out[sv.x] * norm_in[dv.x] * wv.x;
        ov.y = norm_out[sv.y] * norm_in[dv.y] * wv.y;
        ov.z = norm_out[sv.z] * norm_in[dv.z] * wv.z;
        ov.w = norm_out[sv.w] * norm_in[dv.w] * wv.w;
        __builtin_nontemporal_store(ov, (ntf4*)(out + i4));
    } else if (i4 < E) {
        for (long long j = i4; j < E; ++j) {
            out[j] = norm_out[src[j]] * norm_in[dst[j]] * w[j];
        }
    }
}

extern "C" void kernel_launch(void* const* d_in, const int* in_sizes, int n_in,
                              void* d_out, int out_size, void* d_ws, size_t ws_size,
                              hipStream_t stream) {
    const float* edge_weight = (const float*)d_in[0];
    const int*   src         = (const int*)d_in[1];
    const int*   dst         = (const int*)d_in[2];
    const int*   pN          = (const int*)d_in[3];  // 1-element device array
    float* out = (float*)d_out;
    const int E = in_sizes[0];
    float* ws = (float*)d_ws;
    unsigned long long wsb = (unsigned long long)ws_size;

    int nBlocksEdges = (E / 4 + TPB - 1) / TPB;

    ewn_zero_kernel<<<1024, TPB, 0, stream>>>(ws, pN, wsb);
    ewn_scatter_kernel<<<SCAT_GRID, SCAT_TPB, 0, stream>>>(edge_weight, src, dst, ws, pN, wsb, E);
    ewn_reduce_norm_kernel<<<1024, TPB, 0, stream>>>(ws, pN, wsb);
    ewn_gather_kernel<<<nBlocksEdges, TPB, 0, stream>>>(edge_weight, src, dst, ws, pN, out, E);
}

// Round 4
// 699.095 us; speedup vs baseline: 4.1097x; 1.0181x over previous
//
#include <hip/hip_runtime.h>

#define TPB 256

// clang ext_vector types for nontemporal builtins (HIP_vector_type is rejected)
typedef float ntf4 __attribute__((ext_vector_type(4)));
typedef int   nti4 __attribute__((ext_vector_type(4)));

// ---- LDS-binned scatter parameters ----
// One block per CU using (nearly) the full 160 KiB LDS:
// 2 slabs x 20352 x 4B = 162816 B <= 163840 B (gfx950 LDS/CU).
// NR = ceil(100000/20352) = 5 scans of the edge list.
#define SCAT_TPB 1024
#define S_RANGE  20352
#define SCAT_GRID 255       // NR(5) * M(51), all co-resident at 1 block/CU

__device__ __forceinline__ unsigned xcc_id() {
    unsigned v;
    asm volatile("s_getreg_b32 %0, hwreg(HW_REG_XCC_ID)" : "=s"(v));
    return v & 7u;
}

// replicas: R copies of [out_deg (N) | in_deg (N)] back to back in ws.
// R computed identically on device in every kernel: min(8, ws_floats/(2N)).
__device__ __forceinline__ int calc_R(unsigned long long ws_bytes, int N) {
    unsigned long long ws_floats = ws_bytes / 4ull;
    unsigned long long r = ws_floats / (unsigned long long)(2 * N);
    if (r > 8ull) r = 8ull;
    if (r < 1ull) r = 1ull;
    return (int)r;
}

// ---- kernel 1: zero R*2N floats of replica space ----
__global__ void ewn_zero_kernel(float* __restrict__ ws,
                                const int* __restrict__ pN,
                                unsigned long long ws_bytes) {
    int N = *pN;
    int R = calc_R(ws_bytes, N);
    long long total = (long long)R * 2 * N;
    for (long long i = blockIdx.x * (long long)blockDim.x + threadIdx.x; i < total;
         i += (long long)gridDim.x * blockDim.x) {
        ws[i] = 0.0f;
    }
}

// ---- kernel 2: node-range-partitioned LDS histogram scatter ----
// Latency-bound at 16 waves/CU (45% occ, HBM 32%, VALU 10%): fix is MLP.
// Unroll x4 with batch-strided loads (each batch is a fully-coalesced
// dwordx4 per lane); 12 loads issued per iteration -> 192 B/lane in flight.
__global__ __launch_bounds__(SCAT_TPB, 4) void ewn_scatter_kernel(
        const float* __restrict__ w,
        const int* __restrict__ src,
        const int* __restrict__ dst,
        float* __restrict__ ws,
        const int* __restrict__ pN,
        unsigned long long ws_bytes,
        int E) {
    __shared__ float h_out[S_RANGE];
    __shared__ float h_in[S_RANGE];

    const int N = *pN;
    const int R = calc_R(ws_bytes, N);

    int NR = (N + S_RANGE - 1) / S_RANGE;   // 5 for N=100K
    if (NR < 1) NR = 1;
    int M = (int)gridDim.x / NR;            // 51 stripes
    if (M < 1) M = 1;

    const int bid = blockIdx.x;
    if (bid >= NR * M) return;
    const int m = bid / NR;                 // stripe index
    const int r = bid % NR;                 // node-range index
    const int lo = r * S_RANGE;

    // zero LDS histograms
    for (int i = threadIdx.x; i < S_RANGE; i += SCAT_TPB) {
        h_out[i] = 0.0f;
        h_in[i]  = 0.0f;
    }
    __syncthreads();

    // stripe bounds, 4-element aligned so float4/int4 loads stay 16B-aligned
    long long stripe = (((long long)E + M - 1) / M + 3ll) & ~3ll;
    long long jstart = (long long)m * stripe;
    long long jend   = jstart + stripe;
    if (jend > E) jend = E;

    const long long STEP = (long long)SCAT_TPB * 4;

#define EWN_PROC(wv, sv, dv) do {                                                        \
        int t_;                                                                          \
        t_ = sv.x - lo; if ((unsigned)t_ < (unsigned)S_RANGE) unsafeAtomicAdd(&h_out[t_], wv.x); \
        t_ = sv.y - lo; if ((unsigned)t_ < (unsigned)S_RANGE) unsafeAtomicAdd(&h_out[t_], wv.y); \
        t_ = sv.z - lo; if ((unsigned)t_ < (unsigned)S_RANGE) unsafeAtomicAdd(&h_out[t_], wv.z); \
        t_ = sv.w - lo; if ((unsigned)t_ < (unsigned)S_RANGE) unsafeAtomicAdd(&h_out[t_], wv.w); \
        t_ = dv.x - lo; if ((unsigned)t_ < (unsigned)S_RANGE) unsafeAtomicAdd(&h_in[t_],  wv.x); \
        t_ = dv.y - lo; if ((unsigned)t_ < (unsigned)S_RANGE) unsafeAtomicAdd(&h_in[t_],  wv.y); \
        t_ = dv.z - lo; if ((unsigned)t_ < (unsigned)S_RANGE) unsafeAtomicAdd(&h_in[t_],  wv.z); \
        t_ = dv.w - lo; if ((unsigned)t_ < (unsigned)S_RANGE) unsafeAtomicAdd(&h_in[t_],  wv.w); \
    } while (0)

    long long j0 = jstart + (long long)threadIdx.x * 4;

    // main loop: 4 independent coalesced batches per iteration
    for (; j0 + 3 * STEP + 3 < jend; j0 += 4 * STEP) {
        float4 wv0 = *(const float4*)(w + j0);
        int4   sv0 = *(const int4*)(src + j0);
        int4   dv0 = *(const int4*)(dst + j0);
        float4 wv1 = *(const float4*)(w + j0 + STEP);
        int4   sv1 = *(const int4*)(src + j0 + STEP);
        int4   dv1 = *(const int4*)(dst + j0 + STEP);
        float4 wv2 = *(const float4*)(w + j0 + 2 * STEP);
        int4   sv2 = *(const int4*)(src + j0 + 2 * STEP);
        int4   dv2 = *(const int4*)(dst + j0 + 2 * STEP);
        float4 wv3 = *(const float4*)(w + j0 + 3 * STEP);
        int4   sv3 = *(const int4*)(src + j0 + 3 * STEP);
        int4   dv3 = *(const int4*)(dst + j0 + 3 * STEP);
        EWN_PROC(wv0, sv0, dv0);
        EWN_PROC(wv1, sv1, dv1);
        EWN_PROC(wv2, sv2, dv2);
        EWN_PROC(wv3, sv3, dv3);
    }
    // remainder: single batches
    for (; j0 + 3 < jend; j0 += STEP) {
        float4 wv = *(const float4*)(w + j0);
        int4   sv = *(const int4*)(src + j0);
        int4   dv = *(const int4*)(dst + j0);
        EWN_PROC(wv, sv, dv);
    }
    // scalar tail (only if E not a multiple of 4)
    if (j0 < jend) {
        for (long long j = j0; j < jend; ++j) {
            float wj = w[j];
            int t;
            t = src[j] - lo; if ((unsigned)t < (unsigned)S_RANGE) unsafeAtomicAdd(&h_out[t], wj);
            t = dst[j] - lo; if ((unsigned)t < (unsigned)S_RANGE) unsafeAtomicAdd(&h_in[t],  wj);
        }
    }
#undef EWN_PROC
    __syncthreads();

    // flush LDS histograms with coalesced atomics into per-XCD replica
    const unsigned xcc = xcc_id();
    int hi = N - lo;
    if (hi > S_RANGE) hi = S_RANGE;

    if (R == 8) {
        float* deg_out = ws + (unsigned long long)xcc * 2ull * N;
        float* deg_in  = deg_out + N;
        for (int i = threadIdx.x; i < hi; i += SCAT_TPB) {
            __hip_atomic_fetch_add(&deg_out[lo + i], h_out[i], __ATOMIC_RELAXED, __HIP_MEMORY_SCOPE_WORKGROUP);
            __hip_atomic_fetch_add(&deg_in[lo + i],  h_in[i],  __ATOMIC_RELAXED, __HIP_MEMORY_SCOPE_WORKGROUP);
        }
    } else {
        // fallback (ws too small for 8 replicas): device-scope atomics, always correct
        float* deg_out = ws + (unsigned long long)(xcc % (unsigned)R) * 2ull * N;
        float* deg_in  = deg_out + N;
        for (int i = threadIdx.x; i < hi; i += SCAT_TPB) {
            atomicAdd(&deg_out[lo + i], h_out[i]);
            atomicAdd(&deg_in[lo + i],  h_in[i]);
        }
    }
}

// ---- kernel 3: reduce R replicas + rsqrt, result into replica 0 ----
__global__ void ewn_reduce_norm_kernel(float* __restrict__ ws,
                                       const int* __restrict__ pN,
                                       unsigned long long ws_bytes) {
    int N = *pN;
    int R = calc_R(ws_bytes, N);
    long long n2 = 2ll * N;
    for (long long i = blockIdx.x * (long long)blockDim.x + threadIdx.x; i < n2;
         i += (long long)gridDim.x * blockDim.x) {
        float s = 0.0f;
        for (int r = 0; r < R; ++r) s += ws[(long long)r * n2 + i];
        ws[i] = 1.0f / sqrtf(s);   // precise rsqrt to stay under absmax threshold
    }
}

// ---- kernel 4: out[e] = norm_out[src[e]] * norm_in[dst[e]] * w[e] ----
// Two batch-strided 4-edge groups per thread: 6 nt stream loads + 16 table
// gathers issued before any FMA -> 2x the MLP of the old 1-batch version.
// Edge streams are non-temporal so the 800 KB norm tables stay L2-resident.
__global__ void ewn_gather_kernel(const float* __restrict__ w,
                                  const int* __restrict__ src,
                                  const int* __restrict__ dst,
                                  const float* __restrict__ ws,
                                  const int* __restrict__ pN,
                                  float* __restrict__ out,
                                  int E) {
    const int N = *pN;
    const float* norm_out = ws;
    const float* norm_in  = ws + N;

    const long long tid  = (long long)blockIdx.x * blockDim.x + threadIdx.x;
    const long long half = (long long)gridDim.x * blockDim.x * 4;  // elems per batch sweep
    long long ia = tid * 4;
    long long ib = ia + half;

    if (ib + 3 < E) {
        // fast path: both batches fully in range
        ntf4 wva = __builtin_nontemporal_load((const ntf4*)(w + ia));
        nti4 sva = __builtin_nontemporal_load((const nti4*)(src + ia));
        nti4 dva = __builtin_nontemporal_load((const nti4*)(dst + ia));
        ntf4 wvb = __builtin_nontemporal_load((const ntf4*)(w + ib));
        nti4 svb = __builtin_nontemporal_load((const nti4*)(src + ib));
        nti4 dvb = __builtin_nontemporal_load((const nti4*)(dst + ib));
        float sa0 = norm_out[sva.x], sa1 = norm_out[sva.y], sa2 = norm_out[sva.z], sa3 = norm_out[sva.w];
        float da0 = norm_in[dva.x],  da1 = norm_in[dva.y],  da2 = norm_in[dva.z],  da3 = norm_in[dva.w];
        float sb0 = norm_out[svb.x], sb1 = norm_out[svb.y], sb2 = norm_out[svb.z], sb3 = norm_out[svb.w];
        float db0 = norm_in[dvb.x],  db1 = norm_in[dvb.y],  db2 = norm_in[dvb.z],  db3 = norm_in[dvb.w];
        ntf4 ova, ovb;
        ova.x = sa0 * da0 * wva.x;
        ova.y = sa1 * da1 * wva.y;
        ova.z = sa2 * da2 * wva.z;
        ova.w = sa3 * da3 * wva.w;
        ovb.x = sb0 * db0 * wvb.x;
        ovb.y = sb1 * db1 * wvb.y;
        ovb.z = sb2 * db2 * wvb.z;
        ovb.w = sb3 * db3 * wvb.w;
        __builtin_nontemporal_store(ova, (ntf4*)(out + ia));
        __builtin_nontemporal_store(ovb, (ntf4*)(out + ib));
    } else {
        // tail: per-batch with guards
        for (int b = 0; b < 2; ++b) {
            long long i4 = b ? ib : ia;
            if (i4 + 3 < E) {
                ntf4 wv = __builtin_nontemporal_load((const ntf4*)(w + i4));
                nti4 sv = __builtin_nontemporal_load((const nti4*)(src + i4));
                nti4 dv = __builtin_nontemporal_load((const nti4*)(dst + i4));
                ntf4 ov;
                ov.x = norm_out[sv.x] * norm_in[dv.x] * wv.x;
                ov.y = norm_out[sv.y] * norm_in[dv.y] * wv.y;
                ov.z = norm_out[sv.z] * norm_in[dv.z] * wv.z;
                ov.w = norm_out[sv.w] * norm_in[dv.w] * wv.w;
                __builtin_nontemporal_store(ov, (ntf4*)(out + i4));
            } else if (i4 < E) {
                for (long long j = i4; j < E && j < i4 + 4; ++j) {
                    out[j] = norm_out[src[j]] * norm_in[dst[j]] * w[j];
                }
            }
        }
    }
}

extern "C" void kernel_launch(void* const* d_in, const int* in_sizes, int n_in,
                              void* d_out, int out_size, void* d_ws, size_t ws_size,
                              hipStream_t stream) {
    const float* edge_weight = (const float*)d_in[0];
    const int*   src         = (const int*)d_in[1];
    const int*   dst         = (const int*)d_in[2];
    const int*   pN          = (const int*)d_in[3];  // 1-element device array
    float* out = (float*)d_out;
    const int E = in_sizes[0];
    float* ws = (float*)d_ws;
    unsigned long long wsb = (unsigned long long)ws_size;

    // gather: 8 edges per thread (2 batch-strided groups of 4)
    int nBlocksGather = (int)(((long long)E / 8 + TPB - 1) / TPB);
    if (nBlocksGather < 1) nBlocksGather = 1;

    ewn_zero_kernel<<<1024, TPB, 0, stream>>>(ws, pN, wsb);
    ewn_scatter_kernel<<<SCAT_GRID, SCAT_TPB, 0, stream>>>(edge_weight, src, dst, ws, pN, wsb, E);
    ewn_reduce_norm_kernel<<<1024, TPB, 0, stream>>>(ws, pN, wsb);
    ewn_gather_kernel<<<nBlocksGather, TPB, 0, stream>>>(edge_weight, src, dst, ws, pN, out, E);
}